// Round 3
// baseline (433.722 us; speedup 1.0000x reference)
//
#include <hip/hip_runtime.h>
#include <stdint.h>

#define BB 16
#define NN 2048
#define CC 80
#define CONF_THRV 0.5f
#define NMS_THRV 0.5f

// ---------------- kernel 0: class argmax/max + sort keys -------------------
__global__ void k_classify(const float* __restrict__ logits,
                           const float* __restrict__ obj,
                           float* __restrict__ conf0,
                           int* __restrict__ cls0,
                           unsigned long long* __restrict__ keys) {
  int idx = blockIdx.x * blockDim.x + threadIdx.x;
  if (idx >= BB * NN) return;
  const float4* lp = (const float4*)(logits + (size_t)idx * CC);
  float best = -INFINITY;
  int bi = 0;
  #pragma unroll
  for (int q = 0; q < CC / 4; ++q) {
    float4 v = lp[q];
    if (v.x > best) { best = v.x; bi = 4 * q + 0; }
    if (v.y > best) { best = v.y; bi = 4 * q + 1; }
    if (v.z > best) { best = v.z; bi = 4 * q + 2; }
    if (v.w > best) { best = v.w; bi = 4 * q + 3; }
  }
  conf0[idx] = best;
  cls0[idx] = bi;
  float o = obj[idx];
  float s = (o > CONF_THRV) ? o : -INFINITY;
  unsigned u = __float_as_uint(s);
  u = (u & 0x80000000u) ? ~u : (u | 0x80000000u);
  unsigned n = (unsigned)(idx & (NN - 1));
  // descending sort key: score major, smaller original index first on ties
  keys[idx] = ((unsigned long long)u << 32) | (unsigned long long)(0xFFFFFFFFu - n);
}

// ---------------- kernel 1: per-batch bitonic sort + gather ----------------
__global__ __launch_bounds__(1024) void k_sort_gather(
    const float4* __restrict__ boxes,          // [B][N] cx,cy,w,h
    const float* __restrict__ obj,             // [B][N]
    const float* __restrict__ conf0,
    const int* __restrict__ cls0,
    const unsigned long long* __restrict__ keys,
    float4* __restrict__ sxyxy,
    float* __restrict__ sarea,
    float* __restrict__ sobj,
    float* __restrict__ sconf,
    int* __restrict__ scls,
    int* __restrict__ nvalid) {
  __shared__ unsigned long long sk[NN];
  __shared__ int cnt;
  int b = blockIdx.x;
  int t = threadIdx.x;
  if (t == 0) cnt = 0;
  size_t base = (size_t)b * NN;
  sk[t] = keys[base + t];
  sk[t + 1024] = keys[base + t + 1024];
  __syncthreads();
  // bitonic sort, descending
  for (unsigned k = 2; k <= NN; k <<= 1) {
    for (unsigned j = k >> 1; j > 0; j >>= 1) {
      #pragma unroll
      for (int rep = 0; rep < 2; ++rep) {
        unsigned e = (unsigned)t + (unsigned)rep * 1024u;
        unsigned ixj = e ^ j;
        if (ixj > e) {
          unsigned long long a = sk[e], c = sk[ixj];
          bool up = ((e & k) == 0);
          bool doswap = up ? (a < c) : (a > c);   // descending overall
          if (doswap) { sk[e] = c; sk[ixj] = a; }
        }
      }
      __syncthreads();
    }
  }
  int localvalid = 0;
  #pragma unroll
  for (int rep = 0; rep < 2; ++rep) {
    int e = t + rep * 1024;
    unsigned long long key = sk[e];
    unsigned id = 0xFFFFFFFFu - (unsigned)(key & 0xFFFFFFFFull);
    float4 bx = boxes[base + id];
    float hw = bx.z / 2.0f, hh = bx.w / 2.0f;
    float x1 = bx.x - hw, y1 = bx.y - hh;
    float x2 = bx.x + hw, y2 = bx.y + hh;
    float o = obj[base + id];
    sxyxy[base + e] = make_float4(x1, y1, x2, y2);
    sarea[base + e] = __fmul_rn(x2 - x1 + 1.0f, y2 - y1 + 1.0f);
    sobj[base + e] = o;
    sconf[base + e] = conf0[base + id];
    scls[base + e] = cls0[base + id];
    if (o > CONF_THRV) localvalid++;
  }
  atomicAdd(&cnt, localvalid);
  __syncthreads();
  if (t == 0) nvalid[b] = cnt;
}

// ---------------- kernel 2: suppression masks (upper triangle) -------------
__global__ void k_masks(const float4* __restrict__ sxyxy,
                        const float* __restrict__ sarea,
                        const int* __restrict__ scls,
                        const int* __restrict__ nvalid,
                        uint32_t* __restrict__ masks) {
  int b = blockIdx.y;
  int pair = blockIdx.x * blockDim.x + threadIdx.x;  // [0, N*64)
  int i = pair >> 6;
  int w = pair & 63;
  int nv = nvalid[b];
  if (i >= nv) return;                  // rows >= nvalid are never read
  size_t base = (size_t)b * NN;
  uint32_t bits = 0;
  int j0 = w * 32;
  int jend = min(j0 + 32, nv);          // bits for j >= nvalid are irrelevant
  int jstart = max(j0, i + 1);          // only j > i can be suppressed
  if (jstart < jend) {
    float4 bi = sxyxy[base + i];
    float ai = sarea[base + i];
    int ci = scls[base + i];
    for (int j = jstart; j < jend; ++j) {
      float4 bj = sxyxy[base + j];
      float xx1 = fmaxf(bi.x, bj.x);
      float yy1 = fmaxf(bi.y, bj.y);
      float xx2 = fminf(bi.z, bj.z);
      float yy2 = fminf(bi.w, bj.w);
      float cw = fmaxf(xx2 - xx1 + 1.0f, 0.0f);
      float ch = fmaxf(yy2 - yy1 + 1.0f, 0.0f);
      float inter = __fmul_rn(cw, ch);               // block fp-contract
      float aj = sarea[base + j];
      float denom = (ai + aj) - inter;               // same assoc as reference
      float iou = inter / denom;
      if (iou >= NMS_THRV && scls[base + j] == ci) bits |= (1u << (j - j0));
    }
  }
  masks[((size_t)b * NN + i) * 64 + w] = bits;
}

// ---------------- kernel 3: chunked greedy scan ----------------------------
// One wave per batch; lane l owns remv word l (32 rows). Rows processed in
// chunks of 32. Since masks are strictly upper-triangular, the intra-chunk
// suppression lives entirely in lane c's 32 loaded words. If that diagonal
// block is all-zero (overwhelmingly common: suppression is rare), the chunk
// resolves with NO serial per-bit chain:
//   diag==0 && word_c==0 : all 32 rows alive -> remv |= OR(rows)
//   diag==0 && word_c!=0 : alive set known upfront -> predicated ORs
//   diag!=0 (rare)       : bit-serial, but broadcasts issued in parallel
// Depth-4 chunk pipeline hides the mask-row load latency.
__global__ __launch_bounds__(64) void k_scan(const uint32_t* __restrict__ masks,
                                             const int* __restrict__ nvalid,
                                             uint32_t* __restrict__ remv_out) {
  int b = blockIdx.x;
  int lane = threadIdx.x;
  int nv = nvalid[b];
  int nch = (nv + 31) >> 5;
  const uint32_t* mrow = masks + (size_t)b * NN * 64 + lane;
  uint32_t remv = 0;
  const int P = 4;                       // pipeline depth (chunks)
  uint32_t w[P][32];
  #pragma unroll
  for (int p = 0; p < P; ++p) {
    #pragma unroll
    for (int d = 0; d < 32; ++d) {
      int r = p * 32 + d;
      w[p][d] = (r < nv) ? mrow[(size_t)r * 64] : 0u;
    }
  }
  for (int c = 0; c < nch; ++c) {
    int slot = c & (P - 1);
    uint32_t cur[32];
    #pragma unroll
    for (int d = 0; d < 32; ++d) cur[d] = w[slot][d];
    // refill this slot with chunk c+P (off the dependence chain)
    #pragma unroll
    for (int d = 0; d < 32; ++d) {
      int r = (c + P) * 32 + d;
      w[slot][d] = (r < nv) ? mrow[(size_t)r * 64] : 0u;
    }
    // OR-tree of the 32 rows (independent of remv chain)
    uint32_t all_or = 0;
    #pragma unroll
    for (int d = 0; d < 32; ++d) all_or |= cur[d];
    uint32_t word_c = (uint32_t)__shfl((int)remv, c, 64);
    uint32_t diag   = (uint32_t)__shfl((int)all_or, c, 64);
    if (diag == 0u) {
      if (word_c == 0u) {
        remv |= all_or;                          // fast path: all alive
      } else {
        uint32_t acc = 0;
        #pragma unroll
        for (int d = 0; d < 32; ++d)
          acc |= ((word_c >> d) & 1u) ? 0u : cur[d];
        remv |= acc;                             // alive set known upfront
      }
    } else {
      // rare: intra-chunk suppression. Broadcasts are independent of the
      // serial wc chain, so they pipeline.
      uint32_t wc = word_c;
      uint32_t acc = 0;
      #pragma unroll
      for (int d = 0; d < 32; ++d) {
        uint32_t dd = (uint32_t)__shfl((int)cur[d], c, 64);
        if (((wc >> d) & 1u) == 0u) {            // row 32c+d alive
          wc |= dd;                              // propagate intra-chunk
          acc |= cur[d];
        }
      }
      remv |= acc;
    }
  }
  remv_out[b * 64 + lane] = remv;
}

// ---------------- kernel 4: output write -----------------------------------
__global__ void k_write(const float4* __restrict__ sxyxy,
                        const float* __restrict__ sobj,
                        const float* __restrict__ sconf,
                        const int* __restrict__ scls,
                        const uint32_t* __restrict__ remv,
                        const int* __restrict__ nvalid,
                        float* __restrict__ out) {
  int idx = blockIdx.x * blockDim.x + threadIdx.x;
  if (idx >= BB * NN) return;
  int b = idx >> 11;
  int r = idx & (NN - 1);
  bool keep = false;
  if (r < nvalid[b]) {
    uint32_t wrd = remv[b * 64 + (r >> 5)];
    keep = !((wrd >> (r & 31)) & 1u);
  }
  float4 xy = make_float4(0.f, 0.f, 0.f, 0.f);
  float o = 0.f, cf = 0.f, cl = 0.f;
  if (keep) {
    xy = sxyxy[idx];
    o = sobj[idx];
    cf = sconf[idx];
    cl = (float)scls[idx];
  }
  float4* op = (float4*)(out + (size_t)idx * 8);
  op[0] = make_float4((float)b, xy.x, xy.y, xy.z);
  op[1] = make_float4(xy.w, o, cf, cl);
}

extern "C" void kernel_launch(void* const* d_in, const int* in_sizes, int n_in,
                              void* d_out, int out_size, void* d_ws, size_t ws_size,
                              hipStream_t stream) {
  const float4* boxes = (const float4*)d_in[0];        // [B][N][4]
  const float* obj = (const float*)d_in[1];            // [B][N]
  const float* logits = (const float*)d_in[2];         // [B][N][80]
  float* out = (float*)d_out;                          // [B][N][8]

  char* ws = (char*)d_ws;
  size_t off = 0;
  float4* sxyxy = (float4*)(ws + off);            off += (size_t)BB * NN * 16;
  unsigned long long* keys = (unsigned long long*)(ws + off); off += (size_t)BB * NN * 8;
  float* conf0 = (float*)(ws + off);              off += (size_t)BB * NN * 4;
  int* cls0 = (int*)(ws + off);                   off += (size_t)BB * NN * 4;
  float* sarea = (float*)(ws + off);              off += (size_t)BB * NN * 4;
  float* sobj = (float*)(ws + off);               off += (size_t)BB * NN * 4;
  float* sconf = (float*)(ws + off);              off += (size_t)BB * NN * 4;
  int* scls = (int*)(ws + off);                   off += (size_t)BB * NN * 4;
  int* nvalid = (int*)(ws + off);                 off += 256;
  uint32_t* remv = (uint32_t*)(ws + off);         off += (size_t)BB * 64 * 4;
  uint32_t* masks = (uint32_t*)(ws + off);        off += (size_t)BB * NN * 64 * 4;

  hipLaunchKernelGGL(k_classify, dim3((BB * NN + 255) / 256), dim3(256), 0, stream,
                     logits, obj, conf0, cls0, keys);
  hipLaunchKernelGGL(k_sort_gather, dim3(BB), dim3(1024), 0, stream,
                     boxes, obj, conf0, cls0, keys,
                     sxyxy, sarea, sobj, sconf, scls, nvalid);
  hipLaunchKernelGGL(k_masks, dim3(NN * 64 / 256, BB), dim3(256), 0, stream,
                     sxyxy, sarea, scls, nvalid, masks);
  hipLaunchKernelGGL(k_scan, dim3(BB), dim3(64), 0, stream,
                     masks, nvalid, remv);
  hipLaunchKernelGGL(k_write, dim3((BB * NN + 255) / 256), dim3(256), 0, stream,
                     sxyxy, sobj, sconf, scls, remv, nvalid, out);
}

// Round 4
// 157.814 us; speedup vs baseline: 2.7483x; 2.7483x over previous
//
#include <hip/hip_runtime.h>
#include <stdint.h>

#define BB 16
#define NN 2048
#define CC 80
#define CONF_THRV 0.5f
#define NMS_THRV 0.5f

// ---------------- kernel 0: class argmax/max + sort keys -------------------
__global__ void k_classify(const float* __restrict__ logits,
                           const float* __restrict__ obj,
                           float* __restrict__ conf0,
                           int* __restrict__ cls0,
                           unsigned long long* __restrict__ keys) {
  int idx = blockIdx.x * blockDim.x + threadIdx.x;
  if (idx >= BB * NN) return;
  const float4* lp = (const float4*)(logits + (size_t)idx * CC);
  float best = -INFINITY;
  int bi = 0;
  #pragma unroll
  for (int q = 0; q < CC / 4; ++q) {
    float4 v = lp[q];
    if (v.x > best) { best = v.x; bi = 4 * q + 0; }
    if (v.y > best) { best = v.y; bi = 4 * q + 1; }
    if (v.z > best) { best = v.z; bi = 4 * q + 2; }
    if (v.w > best) { best = v.w; bi = 4 * q + 3; }
  }
  conf0[idx] = best;
  cls0[idx] = bi;
  float o = obj[idx];
  float s = (o > CONF_THRV) ? o : -INFINITY;
  unsigned u = __float_as_uint(s);
  u = (u & 0x80000000u) ? ~u : (u | 0x80000000u);
  unsigned n = (unsigned)(idx & (NN - 1));
  // descending sort key: score major, smaller original index first on ties
  keys[idx] = ((unsigned long long)u << 32) | (unsigned long long)(0xFFFFFFFFu - n);
}

// ---------------- kernel 1: per-batch bitonic sort + gather ----------------
__global__ __launch_bounds__(1024) void k_sort_gather(
    const float4* __restrict__ boxes,          // [B][N] cx,cy,w,h
    const float* __restrict__ obj,             // [B][N]
    const float* __restrict__ conf0,
    const int* __restrict__ cls0,
    const unsigned long long* __restrict__ keys,
    float4* __restrict__ sxyxy,
    float* __restrict__ sarea,
    float* __restrict__ sobj,
    float* __restrict__ sconf,
    int* __restrict__ scls,
    int* __restrict__ nvalid) {
  __shared__ unsigned long long sk[NN];
  __shared__ int cnt;
  int b = blockIdx.x;
  int t = threadIdx.x;
  if (t == 0) cnt = 0;
  size_t base = (size_t)b * NN;
  sk[t] = keys[base + t];
  sk[t + 1024] = keys[base + t + 1024];
  __syncthreads();
  // bitonic sort, descending
  for (unsigned k = 2; k <= NN; k <<= 1) {
    for (unsigned j = k >> 1; j > 0; j >>= 1) {
      #pragma unroll
      for (int rep = 0; rep < 2; ++rep) {
        unsigned e = (unsigned)t + (unsigned)rep * 1024u;
        unsigned ixj = e ^ j;
        if (ixj > e) {
          unsigned long long a = sk[e], c = sk[ixj];
          bool up = ((e & k) == 0);
          bool doswap = up ? (a < c) : (a > c);   // descending overall
          if (doswap) { sk[e] = c; sk[ixj] = a; }
        }
      }
      __syncthreads();
    }
  }
  int localvalid = 0;
  #pragma unroll
  for (int rep = 0; rep < 2; ++rep) {
    int e = t + rep * 1024;
    unsigned long long key = sk[e];
    unsigned id = 0xFFFFFFFFu - (unsigned)(key & 0xFFFFFFFFull);
    float4 bx = boxes[base + id];
    float hw = bx.z / 2.0f, hh = bx.w / 2.0f;
    float x1 = bx.x - hw, y1 = bx.y - hh;
    float x2 = bx.x + hw, y2 = bx.y + hh;
    float o = obj[base + id];
    sxyxy[base + e] = make_float4(x1, y1, x2, y2);
    sarea[base + e] = __fmul_rn(x2 - x1 + 1.0f, y2 - y1 + 1.0f);
    sobj[base + e] = o;
    sconf[base + e] = conf0[base + id];
    scls[base + e] = cls0[base + id];
    if (o > CONF_THRV) localvalid++;
  }
  atomicAdd(&cnt, localvalid);
  __syncthreads();
  if (t == 0) nvalid[b] = cnt;
}

// ---------------- kernel 2: suppression masks, TRANSPOSED layout -----------
// masksT[(b*64 + w)*NN + i] = bits for rows j in [32w, 32w+32) suppressed by i.
// Thread mapping: i fast (coalesced reads of box i, coalesced transposed
// writes), w block-uniform (inner-j box loads are wave-uniform -> L1
// broadcast). Rows i >= nv write 0 unconditionally so k_scan needs no guards.
__global__ void k_masks(const float4* __restrict__ sxyxy,
                        const float* __restrict__ sarea,
                        const int* __restrict__ scls,
                        const int* __restrict__ nvalid,
                        uint32_t* __restrict__ masksT) {
  int b = blockIdx.y;
  int pair = blockIdx.x * blockDim.x + threadIdx.x;  // [0, NN*64)
  int i = pair & (NN - 1);
  int w = pair >> 11;
  int nv = nvalid[b];
  size_t base = (size_t)b * NN;
  uint32_t bits = 0;
  int j0 = w * 32;
  int jend = min(j0 + 32, nv);          // bits for j >= nv never set
  int jstart = max(j0, i + 1);          // only j > i can be suppressed
  if (i < nv && jstart < jend) {
    float4 bi = sxyxy[base + i];
    float ai = sarea[base + i];
    int ci = scls[base + i];
    for (int j = jstart; j < jend; ++j) {
      float4 bj = sxyxy[base + j];
      float xx1 = fmaxf(bi.x, bj.x);
      float yy1 = fmaxf(bi.y, bj.y);
      float xx2 = fminf(bi.z, bj.z);
      float yy2 = fminf(bi.w, bj.w);
      float cw = fmaxf(xx2 - xx1 + 1.0f, 0.0f);
      float ch = fmaxf(yy2 - yy1 + 1.0f, 0.0f);
      float inter = __fmul_rn(cw, ch);               // block fp-contract
      float aj = sarea[base + j];
      float denom = (ai + aj) - inter;               // same assoc as reference
      float iou = inter / denom;
      if (iou >= NMS_THRV && scls[base + j] == ci) bits |= (1u << (j - j0));
    }
  }
  masksT[((size_t)b * 64 + w) * NN + i] = bits;
}

// ---------------- kernel 3: chunked greedy scan, STATIC pipeline -----------
// One wave per batch; lane l owns remv word l. Rows in chunks of 32; masks
// strictly upper-triangular so intra-chunk suppression lives in lane c's
// words. diag==0 (common): no per-bit chain. Four NAMED buffers + 4x-unrolled
// loop => every array index is compile-time constant => stays in VGPRs
// (round-3 regression was dynamic-index scratch demotion: VGPR=24,
// WRITE_SIZE=516KB).
__global__ __launch_bounds__(64) void k_scan(const uint32_t* __restrict__ masksT,
                                             uint32_t* __restrict__ remv_out) {
  int b = blockIdx.x;
  int lane = threadIdx.x;
  const uint4* col = (const uint4*)(masksT + ((size_t)b * 64 + lane) * NN);
  // col[c*8 + q] holds rows 32c+4q .. 32c+4q+3 (word `lane` of each)
  uint32_t remv = 0;
  uint4 A[8], B[8], C[8], D[8];
#define LOADBUF(BUF, CH) do {                                          \
    _Pragma("unroll")                                                  \
    for (int q = 0; q < 8; ++q) BUF[q] = col[(CH) * 8 + q];            \
  } while (0)
  LOADBUF(A, 0); LOADBUF(B, 1); LOADBUF(C, 2); LOADBUF(D, 3);
#define STEP(BUF, CH, RCH) do {                                        \
    uint32_t cur[32];                                                  \
    _Pragma("unroll")                                                  \
    for (int q = 0; q < 8; ++q) {                                      \
      cur[4*q+0] = BUF[q].x; cur[4*q+1] = BUF[q].y;                    \
      cur[4*q+2] = BUF[q].z; cur[4*q+3] = BUF[q].w;                    \
    }                                                                  \
    { int rr = (RCH) < 64 ? (RCH) : 0; LOADBUF(BUF, rr); }             \
    uint32_t all_or = 0;                                               \
    _Pragma("unroll")                                                  \
    for (int d = 0; d < 32; ++d) all_or |= cur[d];                     \
    uint32_t word_c = (uint32_t)__shfl((int)remv, (CH), 64);           \
    uint32_t diag   = (uint32_t)__shfl((int)all_or, (CH), 64);         \
    if (diag == 0u) {                                                  \
      if (word_c == 0u) {                                              \
        remv |= all_or;                       /* all 32 rows alive */  \
      } else {                                                         \
        uint32_t acc = 0;                                              \
        _Pragma("unroll")                                              \
        for (int d = 0; d < 32; ++d)                                   \
          acc |= ((word_c >> d) & 1u) ? 0u : cur[d];                   \
        remv |= acc;                                                   \
      }                                                                \
    } else {                                  /* rare: intra-chunk */  \
      uint32_t wc = word_c, acc = 0;                                   \
      _Pragma("unroll")                                                \
      for (int d = 0; d < 32; ++d) {                                   \
        uint32_t dd = (uint32_t)__shfl((int)cur[d], (CH), 64);         \
        if (((wc >> d) & 1u) == 0u) { wc |= dd; acc |= cur[d]; }       \
      }                                                                \
      remv |= acc;                                                     \
    }                                                                  \
  } while (0)
  for (int c = 0; c < 64; c += 4) {
    STEP(A, c + 0, c + 4);
    STEP(B, c + 1, c + 5);
    STEP(C, c + 2, c + 6);
    STEP(D, c + 3, c + 7);
  }
#undef STEP
#undef LOADBUF
  remv_out[b * 64 + lane] = remv;
}

// ---------------- kernel 4: output write -----------------------------------
__global__ void k_write(const float4* __restrict__ sxyxy,
                        const float* __restrict__ sobj,
                        const float* __restrict__ sconf,
                        const int* __restrict__ scls,
                        const uint32_t* __restrict__ remv,
                        const int* __restrict__ nvalid,
                        float* __restrict__ out) {
  int idx = blockIdx.x * blockDim.x + threadIdx.x;
  if (idx >= BB * NN) return;
  int b = idx >> 11;
  int r = idx & (NN - 1);
  bool keep = false;
  if (r < nvalid[b]) {
    uint32_t wrd = remv[b * 64 + (r >> 5)];
    keep = !((wrd >> (r & 31)) & 1u);
  }
  float4 xy = make_float4(0.f, 0.f, 0.f, 0.f);
  float o = 0.f, cf = 0.f, cl = 0.f;
  if (keep) {
    xy = sxyxy[idx];
    o = sobj[idx];
    cf = sconf[idx];
    cl = (float)scls[idx];
  }
  float4* op = (float4*)(out + (size_t)idx * 8);
  op[0] = make_float4((float)b, xy.x, xy.y, xy.z);
  op[1] = make_float4(xy.w, o, cf, cl);
}

extern "C" void kernel_launch(void* const* d_in, const int* in_sizes, int n_in,
                              void* d_out, int out_size, void* d_ws, size_t ws_size,
                              hipStream_t stream) {
  const float4* boxes = (const float4*)d_in[0];        // [B][N][4]
  const float* obj = (const float*)d_in[1];            // [B][N]
  const float* logits = (const float*)d_in[2];         // [B][N][80]
  float* out = (float*)d_out;                          // [B][N][8]

  char* ws = (char*)d_ws;
  size_t off = 0;
  float4* sxyxy = (float4*)(ws + off);            off += (size_t)BB * NN * 16;
  unsigned long long* keys = (unsigned long long*)(ws + off); off += (size_t)BB * NN * 8;
  float* conf0 = (float*)(ws + off);              off += (size_t)BB * NN * 4;
  int* cls0 = (int*)(ws + off);                   off += (size_t)BB * NN * 4;
  float* sarea = (float*)(ws + off);              off += (size_t)BB * NN * 4;
  float* sobj = (float*)(ws + off);               off += (size_t)BB * NN * 4;
  float* sconf = (float*)(ws + off);              off += (size_t)BB * NN * 4;
  int* scls = (int*)(ws + off);                   off += (size_t)BB * NN * 4;
  int* nvalid = (int*)(ws + off);                 off += 256;
  uint32_t* remv = (uint32_t*)(ws + off);         off += (size_t)BB * 64 * 4;
  uint32_t* masksT = (uint32_t*)(ws + off);       off += (size_t)BB * NN * 64 * 4;

  hipLaunchKernelGGL(k_classify, dim3((BB * NN + 255) / 256), dim3(256), 0, stream,
                     logits, obj, conf0, cls0, keys);
  hipLaunchKernelGGL(k_sort_gather, dim3(BB), dim3(1024), 0, stream,
                     boxes, obj, conf0, cls0, keys,
                     sxyxy, sarea, sobj, sconf, scls, nvalid);
  hipLaunchKernelGGL(k_masks, dim3(NN * 64 / 256, BB), dim3(256), 0, stream,
                     sxyxy, sarea, scls, nvalid, masksT);
  hipLaunchKernelGGL(k_scan, dim3(BB), dim3(64), 0, stream,
                     masksT, remv);
  hipLaunchKernelGGL(k_write, dim3((BB * NN + 255) / 256), dim3(256), 0, stream,
                     sxyxy, sobj, sconf, scls, remv, nvalid, out);
}